// Round 8
// baseline (131.935 us; speedup 1.0000x reference)
//
#include <hip/hip_runtime.h>

#define NB 32
#define NN 64
#define ND 128
#define NE 128
#define NK 64   // output capsules (= NN)

typedef float  f32x4  __attribute__((ext_vector_type(4)));
typedef short  short8 __attribute__((ext_vector_type(8)));
typedef __bf16 bf16x8 __attribute__((ext_vector_type(8)));

union Frag { bf16x8 h; short8 s; };

// u_tmp[j][k][d][b] (k_u's compact-stream output), u[j][d][b][k] (route layout)
static constexpr size_t UT_BYTES = (size_t)NN * NN * ND * NB * 2;  // 33.5 MB
static constexpr size_t U_BYTES  = (size_t)NN * ND * NB * NK * 2;  // 33.5 MB
static constexpr size_t V_BYTES  = (size_t)NB * ND * NK * 4;       // 1 MB
static constexpr size_t WS_NEED  = UT_BYTES + U_BYTES + 2 * V_BYTES;

#define GLOAD16(g, l)                                                   \
    __builtin_amdgcn_global_load_lds(                                   \
        (const __attribute__((address_space(1))) void*)(g),             \
        (__attribute__((address_space(3))) void*)(l), 16, 0, 0)

// ---------------- DPP wave64 sum (VALU pipe) ----------------
template <int CTRL, int RMASK>
__device__ __forceinline__ float dppf(float x) {
    int xi = __float_as_int(x);
    return __int_as_float(__builtin_amdgcn_update_dpp(xi, xi, CTRL, RMASK, 0xF, false));
}
__device__ __forceinline__ float wave_sum(float x) {
    x += dppf<0xB1, 0xF>(x);
    x += dppf<0x4E, 0xF>(x);
    x += dppf<0x141, 0xF>(x);
    x += dppf<0x140, 0xF>(x);
    x += dppf<0x142, 0xA>(x);
    x += dppf<0x143, 0xC>(x);
    return __int_as_float(__builtin_amdgcn_readlane(__float_as_int(x), 63));
}

__device__ __forceinline__ ushort f2bf(float f) {
    __bf16 h = (__bf16)f;
    ushort r;
    __builtin_memcpy(&r, &h, 2);
    return r;
}
__device__ __forceinline__ float bf2f(ushort r) {
    return __int_as_float(((int)r) << 16);
}
__device__ __forceinline__ void cvt8f(const f32x4& a, const f32x4& b, Frag& fr) {
    fr.h[0] = (__bf16)a[0]; fr.h[1] = (__bf16)a[1]; fr.h[2] = (__bf16)a[2]; fr.h[3] = (__bf16)a[3];
    fr.h[4] = (__bf16)b[0]; fr.h[5] = (__bf16)b[1]; fr.h[6] = (__bf16)b[2]; fr.h[7] = (__bf16)b[3];
}

// ---------------- K1: u_tmp[j,k,d,b] = sum_e x[b,j,e] * W[j,k,d,e] ---------
// LOCKSTEP BAND SWEEP: 2048 resident waves (512 blocks x 4, 2 blk/CU).
// Chunk = 8 KB = W[j][k][16 d][128 e] (K-complete). Wave w of j-group takes
// chunk c = i*32 + w: at step i the GPU reads ONE contiguous 16-MB band
// (64 j-slabs x 256 KB advancing together) -> DRAM-page-friendly frontier.
// Per chunk: 8 MFMA (M=32b x N=16d x K=128e), fresh acc, 1-KB contiguous
// output tile. vmcnt schedule counts 2 stores/chunk: i=0 ->8, 1..14 ->10,
// 15 ->4 (in-order retire guarantees stage(i) drained; see ledger).
__global__ __launch_bounds__(256, 2) void k_u(const float* __restrict__ W,
                                              const float* __restrict__ x,
                                              ushort* __restrict__ u_tmp) {
    __shared__ float Wl[4][2][2048];  // per-wave double-buffered 8-KB chunks
    const int t  = threadIdx.x;
    const int wv = t >> 6;
    const int l  = t & 63;
    const int g  = blockIdx.x * 4 + wv;  // 2048 waves
    const int j  = g >> 5;               // 64 j
    const int w  = g & 31;               // 32 waves per j-group

    const int lr = l & 15;  // fragment row (b-row for A, d-row for B)
    const int lh = l >> 4;  // e-slice

    // ---- A fragments: x[b, j, e] (loaded once; x is L2/L3-hot)
    const float* xb = x + (size_t)j * NE;
    f32x4 xf[2][4][2];
#pragma unroll
    for (int mt = 0; mt < 2; ++mt)
#pragma unroll
        for (int ec = 0; ec < 4; ++ec) {
            const float* p = xb + (size_t)(mt * 16 + lr) * (NN * NE) + ec * 32 + lh * 8;
            xf[mt][ec][0] = *reinterpret_cast<const f32x4*>(p);
            xf[mt][ec][1] = *reinterpret_cast<const f32x4*>(p + 4);
        }
    asm volatile("s_waitcnt vmcnt(0)" ::: "memory");
    __builtin_amdgcn_sched_barrier(0);
    Frag a[2][4];
#pragma unroll
    for (int mt = 0; mt < 2; ++mt)
#pragma unroll
        for (int ec = 0; ec < 4; ++ec) cvt8f(xf[mt][ec][0], xf[mt][ec][1], a[mt][ec]);

    // chunk i -> c = i*32 + w; k = c>>3; ds = c&7; 16 d-rows of 512 B.
    // Stage instr i_: rows 2i_,2i_+1 (512-B halves); src granule XOR (row&7)
    // so LDS[row][p] = global[row][p ^ (row&7)] (both-sides swizzle, rule #21).
#define STAGE(ci, buf)                                                         \
    {                                                                          \
        const int c_ = (ci) * 32 + w;                                          \
        const char* base_ = (const char*)W +                                   \
            (((size_t)(j * NN + (c_ >> 3)) * ND + (c_ & 7) * 16) * NE) * 4;    \
        _Pragma("unroll") for (int i_ = 0; i_ < 8; ++i_) {                     \
            const int rl_ = 2 * i_ + (l >> 5);                                 \
            GLOAD16(base_ + rl_ * 512 + (((l & 31) ^ (rl_ & 7)) << 4),         \
                    &Wl[wv][buf][i_ * 256]);                                   \
        }                                                                      \
    }

    STAGE(0, 0);
    STAGE(1, 1);

#pragma unroll
    for (int i = 0; i < 16; ++i) {
        if (i == 0)      { asm volatile("s_waitcnt vmcnt(8)" ::: "memory"); }
        else if (i < 15) { asm volatile("s_waitcnt vmcnt(10)" ::: "memory"); }
        else             { asm volatile("s_waitcnt vmcnt(4)" ::: "memory"); }
        __builtin_amdgcn_sched_barrier(0);

        // B-frags: d-row lr, e-granule G = ec*8+lh*2+h at LDS pos G^(lr&7)
        const char* cb = (const char*)&Wl[wv][i & 1][0];
        f32x4 gq[4][2];
#pragma unroll
        for (int ec = 0; ec < 4; ++ec)
#pragma unroll
            for (int h = 0; h < 2; ++h) {
                const int pos = (ec * 8 + lh * 2 + h) ^ (lr & 7);
                gq[ec][h] = *reinterpret_cast<const f32x4*>(cb + lr * 512 + pos * 16);
            }
        // ds_reads must land before this buffer is re-staged (rule #18)
        asm volatile("s_waitcnt lgkmcnt(0)" ::: "memory");
        __builtin_amdgcn_sched_barrier(0);
        if (i < 14) STAGE(i + 2, i & 1);

        f32x4 acc0 = (f32x4)0.0f, acc1 = (f32x4)0.0f;
#pragma unroll
        for (int ec = 0; ec < 4; ++ec) {
            Frag bw;
            cvt8f(gq[ec][0], gq[ec][1], bw);
            acc0 = __builtin_amdgcn_mfma_f32_16x16x32_bf16(a[0][ec].s, bw.s, acc0, 0, 0, 0);
            acc1 = __builtin_amdgcn_mfma_f32_16x16x32_bf16(a[1][ec].s, bw.s, acc1, 0, 0, 0);
        }

        // store chunk tile [d16][b32] bf16 = 1 KB contiguous at
        // u_tmp + ((j*NN+k)*ND + ds*16)*NB.  D-frag: b=(l>>4)*4+r (+16*mt), d=lr.
        const int c  = i * 32 + w;
        char* op = (char*)u_tmp +
                   (((size_t)(j * NN + (c >> 3)) * ND + (c & 7) * 16) * NB) * 2;
        uint2 pv0, pv1;
        pv0.x = (uint)f2bf(acc0[0]) | ((uint)f2bf(acc0[1]) << 16);
        pv0.y = (uint)f2bf(acc0[2]) | ((uint)f2bf(acc0[3]) << 16);
        pv1.x = (uint)f2bf(acc1[0]) | ((uint)f2bf(acc1[1]) << 16);
        pv1.y = (uint)f2bf(acc1[2]) | ((uint)f2bf(acc1[3]) << 16);
        *reinterpret_cast<uint2*>(op + lr * 64 + lh * 8)      = pv0;  // b 0..15
        *reinterpret_cast<uint2*>(op + lr * 64 + 32 + lh * 8) = pv1;  // b 16..31
    }
#undef STAGE
}

// ---------------- K2: transpose u_tmp[j,k,d,b] -> u[j,d,b,k] ----------------
// block = (j, dq of 16 d). Reads 64 x 1-KB contiguous pieces; writes 1-KB
// contiguous runs. LDS XOR-swizzled (swz = (k ^ k>>3)&7) -> gather reads are
// conflict-free (kg enters the bank index via the swizzle).
__global__ __launch_bounds__(256, 2) void k_t(const ushort* __restrict__ u_tmp,
                                              ushort* __restrict__ u) {
    __shared__ ushort Lt[NN * 512];  // 64 KB: [k][64 granules of 16 B, swizzled]
    const int j  = blockIdx.x >> 3;
    const int dq = blockIdx.x & 7;
    const int t  = threadIdx.x;
    const int l  = t & 63;

#pragma unroll
    for (int it = 0; it < 16; ++it) {
        const int k   = it * 4 + (t >> 6);
        const int swz = (k ^ (k >> 3)) & 7;
        short8 v = *reinterpret_cast<const short8*>(
            u_tmp + ((size_t)(j * NN + k) * ND + dq * 16) * NB + l * 8);
        *reinterpret_cast<short8*>(&Lt[k * 512 + ((l ^ swz) * 8)]) = v;
    }
    __syncthreads();

#pragma unroll
    for (int it = 0; it < 16; ++it) {
        const int p  = it * 256 + t;
        const int kg = p & 7;
        const int b  = (p >> 3) & 31;
        const int dd = p >> 8;
        short8 v;
#pragma unroll
        for (int r = 0; r < 8; ++r) {
            const int k   = kg * 8 + r;
            const int swz = (k ^ (k >> 3)) & 7;
            const int G   = dd * 4 + (b >> 3);
            v[r] = (short)Lt[k * 512 + ((G ^ swz) * 8) + (b & 7)];
        }
        *reinterpret_cast<short8*>(
            u + ((size_t)(j * ND + dq * 16 + dd) * NB + b) * NK + kg * 8) = v;
    }
}

// ---------------- Routing: s[b,d,k] = sum_j softmax_k(u*Vsum) * u ----------
// (verbatim r7; u is [j][d][b][k])
__global__ __launch_bounds__(512) void k_route(const ushort* __restrict__ u,
                                               const float* __restrict__ Vsum,
                                               float* __restrict__ s,
                                               int first) {
    __shared__ float P[8][8][65];
    const int b  = blockIdx.x >> 4;
    const int dg = blockIdx.x & 15;
    const int t  = threadIdx.x;
    const int wv = t >> 6;  // j-group
    const int l  = t & 63;  // k

    float sacc[8];
#pragma unroll
    for (int dd = 0; dd < 8; ++dd) sacc[dd] = 0.0f;

    const size_t JS = (size_t)ND * NB * NK;
    const ushort* ub = u + ((size_t)(wv * 8) * ND + dg * 8) * (NB * NK) +
                       (size_t)b * NK + l;

    if (first) {
        for (int jj = 0; jj < 8; ++jj) {
            const ushort* up = ub + jj * JS;
#pragma unroll
            for (int dd = 0; dd < 8; ++dd) sacc[dd] += bf2f(up[dd * (NB * NK)]);
        }
#pragma unroll
        for (int dd = 0; dd < 8; ++dd) sacc[dd] *= (1.0f / 64.0f);
    } else {
        float vs[8];
#pragma unroll
        for (int dd = 0; dd < 8; ++dd)
            vs[dd] = Vsum[((size_t)b * ND + dg * 8 + dd) * NK + l];

        for (int jj = 0; jj < 8; ++jj) {
            const ushort* up = ub + jj * JS;
            float uv[8];
#pragma unroll
            for (int dd = 0; dd < 8; ++dd) uv[dd] = bf2f(up[dd * (NB * NK)]);
#pragma unroll
            for (int dd = 0; dd < 8; ++dd) {
                float p = __expf(uv[dd] * vs[dd] - 32.0f);
                float q = wave_sum(p);
                sacc[dd] = fmaf(p * __builtin_amdgcn_rcpf(q), uv[dd], sacc[dd]);
            }
        }
    }

#pragma unroll
    for (int dd = 0; dd < 8; ++dd) P[wv][dd][l] = sacc[dd];
    __syncthreads();

    const int dd = t >> 6;
    const int k  = t & 63;
    float r = P[0][dd][k];
#pragma unroll
    for (int w2 = 1; w2 < 8; ++w2) r += P[w2][dd][k];
    s[((size_t)b * ND + dg * 8 + dd) * NK + k] = r;
}

// ---------------- Squash (verbatim r7) -------------------------------------
__global__ __launch_bounds__(256) void k_squash(const float* __restrict__ s,
                                                float* __restrict__ Vsum,
                                                float* __restrict__ out,
                                                int mode) {
    const int t  = threadIdx.x;
    const int gw = blockIdx.x * 4 + (t >> 6);
    const int b  = gw >> 6;
    const int k  = gw & 63;
    const int l  = t & 63;

    const float s0 = s[((size_t)b * ND + l) * NK + k];
    const float s1 = s[((size_t)b * ND + l + 64) * NK + k];
    float sq    = wave_sum(fmaf(s0, s0, s1 * s1));
    float scale = (sq / (1.0f + sq)) * rsqrtf(sq + 1e-9f);
    float v0 = s0 * scale, v1 = s1 * scale;
    if (mode == 2) {
        float* op = out + ((size_t)b * NN + k) * ND;
        op[l]      = v0;
        op[l + 64] = v1;
    } else if (mode == 0) {
        float* vp = Vsum + (size_t)b * ND * NK + k;
        vp[(size_t)l * NK]        = v0;
        vp[(size_t)(l + 64) * NK] = v1;
    } else {
        float* vp = Vsum + (size_t)b * ND * NK + k;
        vp[(size_t)l * NK]        += v0;
        vp[(size_t)(l + 64) * NK] += v1;
    }
}

extern "C" void kernel_launch(void* const* d_in, const int* in_sizes, int n_in,
                              void* d_out, int out_size, void* d_ws, size_t ws_size,
                              hipStream_t stream) {
    (void)in_sizes; (void)n_in; (void)out_size;
    const float* x = (const float*)d_in[0];
    const float* W = (const float*)d_in[1];
    float* out = (float*)d_out;

    if (ws_size < WS_NEED) return;
    char* ws = (char*)d_ws;
    ushort* u_tmp = (ushort*)ws;
    ushort* u     = (ushort*)(ws + UT_BYTES);
    float* Vsum   = (float*)(ws + UT_BYTES + U_BYTES);
    float* s      = (float*)(ws + UT_BYTES + U_BYTES + V_BYTES);

    k_u<<<dim3(512), dim3(256), 0, stream>>>(W, x, u_tmp);
    k_t<<<dim3(512), dim3(256), 0, stream>>>(u_tmp, u);
    for (int it = 0; it < 3; ++it) {
        k_route<<<dim3(512), dim3(512), 0, stream>>>(u, Vsum, s, it == 0 ? 1 : 0);
        k_squash<<<dim3(512), dim3(256), 0, stream>>>(s, Vsum, out, it);
    }
}

// Round 9
// 122.737 us; speedup vs baseline: 1.0749x; 1.0749x over previous
//
#include <hip/hip_runtime.h>

#define NB 32
#define NN 64
#define ND 128
#define NE 128
#define NK 64   // output capsules (= NN)

typedef float  f32x4  __attribute__((ext_vector_type(4)));
typedef short  short8 __attribute__((ext_vector_type(8)));
typedef __bf16 bf16x8 __attribute__((ext_vector_type(8)));

union Frag { bf16x8 h; short8 s; };

// u layout: [j][d][b][k]  (r7) -- wave-(j,d) output tile is one 4KB run
static constexpr size_t U_BYTES = (size_t)NN * ND * NB * NK * 2;  // 33.5 MB
static constexpr size_t V_BYTES = (size_t)NB * ND * NK * 4;       // 1 MB
static constexpr size_t WS_NEED = U_BYTES + 2 * V_BYTES;

// ---------------- DPP wave64 sum (VALU pipe) ----------------
template <int CTRL, int RMASK>
__device__ __forceinline__ float dppf(float x) {
    int xi = __float_as_int(x);
    return __int_as_float(__builtin_amdgcn_update_dpp(xi, xi, CTRL, RMASK, 0xF, false));
}
__device__ __forceinline__ float wave_sum(float x) {
    x += dppf<0xB1, 0xF>(x);
    x += dppf<0x4E, 0xF>(x);
    x += dppf<0x141, 0xF>(x);
    x += dppf<0x140, 0xF>(x);
    x += dppf<0x142, 0xA>(x);
    x += dppf<0x143, 0xC>(x);
    return __int_as_float(__builtin_amdgcn_readlane(__float_as_int(x), 63));
}

__device__ __forceinline__ ushort f2bf(float f) {
    __bf16 h = (__bf16)f;
    ushort r;
    __builtin_memcpy(&r, &h, 2);
    return r;
}
__device__ __forceinline__ float bf2f(ushort r) {
    return __int_as_float(((int)r) << 16);
}
__device__ __forceinline__ void cvt8f(const f32x4& a, const f32x4& b, Frag& fr) {
    fr.h[0] = (__bf16)a[0]; fr.h[1] = (__bf16)a[1]; fr.h[2] = (__bf16)a[2]; fr.h[3] = (__bf16)a[3];
    fr.h[4] = (__bf16)b[0]; fr.h[5] = (__bf16)b[1]; fr.h[6] = (__bf16)b[2]; fr.h[7] = (__bf16)b[3];
}

// ---------------- K1: u[j,d,b,k] = sum_e x[b,j,e] * W[j,k,d,e] (bf16 MFMA) --
// NO LDS in the main loop: each lane loads ITS OWN B-fragment bytes straight
// to VGPRs (fragment needs no cross-lane redistribution), hand-pipelined
// 3 sub-chunks deep (12 dwordx4 in flight/wave). This removes the
// global_load_lds DMA + 2-phase lgkmcnt cadence that capped every r4-r8
// variant at ~11 B/cyc/CU (the m97-plateau signature).
// Sub-chunk sc = (nt, ec-pair): 4 f32x4/lane; MFMA order per acc unchanged
// vs r7 -> u bit-identical.
__global__ __launch_bounds__(256, 3) void k_u(const float* __restrict__ W,
                                              const float* __restrict__ x,
                                              ushort* __restrict__ u) {
    __shared__ ushort T[4][32][72];  // epilogue-only transpose tile
    const int t  = threadIdx.x;
    const int wv = t >> 6;
    const int l  = t & 63;
    const int gw = blockIdx.x * 4 + wv;
    const int j  = gw >> 7;
    const int d  = gw & 127;

    const int lr = l & 15;  // fragment row (b-row for A, k-row for B)
    const int lh = l >> 4;  // e-slice

    // ---- A fragments: x[b, j, e], row = b (x is 1 MB, L2/L3-hot)
    const float* xb = x + (size_t)j * NE;
    Frag a[2][4];
    {
        f32x4 xf[2][4][2];
#pragma unroll
        for (int mt = 0; mt < 2; ++mt)
#pragma unroll
            for (int ec = 0; ec < 4; ++ec) {
                const float* p = xb + (size_t)(mt * 16 + lr) * (NN * NE) + ec * 32 + lh * 8;
                xf[mt][ec][0] = *reinterpret_cast<const f32x4*>(p);
                xf[mt][ec][1] = *reinterpret_cast<const f32x4*>(p + 4);
            }
#pragma unroll
        for (int mt = 0; mt < 2; ++mt)
#pragma unroll
            for (int ec = 0; ec < 4; ++ec) cvt8f(xf[mt][ec][0], xf[mt][ec][1], a[mt][ec]);
    }

    // per-lane B base: k-row = lr (+16*nt via big stride), e-slice = lh*8
    const float* pB = W + (((size_t)j * NN + lr) * ND + d) * NE + lh * 8;

    // sub-chunk sc: nt = sc>>1, ec = (sc&1)*2 + q (q=0,1), halves h=0,1
#define LOADSC(sc, B)                                                          \
    {                                                                          \
        const float* p_ = pB + (size_t)((sc) >> 1) * (16 * ND * NE) +          \
                          ((sc) & 1) * 64;                                     \
        B[0] = *reinterpret_cast<const f32x4*>(p_);                            \
        B[1] = *reinterpret_cast<const f32x4*>(p_ + 4);                        \
        B[2] = *reinterpret_cast<const f32x4*>(p_ + 32);                       \
        B[3] = *reinterpret_cast<const f32x4*>(p_ + 36);                       \
    }

    f32x4 B0[4], B1[4], B2[4];
    LOADSC(0, B0);
    LOADSC(1, B1);
    LOADSC(2, B2);
    __builtin_amdgcn_sched_barrier(0);

    f32x4 acc[2][4];  // [mt][nt]
#pragma unroll
    for (int mt = 0; mt < 2; ++mt)
#pragma unroll
        for (int nt = 0; nt < 4; ++nt) acc[mt][nt] = (f32x4)0.0f;

    // cvt frees the buffer regs -> reload immediately (3-deep rotation);
    // sched_barrier pins the reload ABOVE the MFMAs.
#define STEP(sc, Bc, PRE)                                                      \
    {                                                                          \
        Frag bw0, bw1;                                                         \
        cvt8f(Bc[0], Bc[1], bw0);                                              \
        cvt8f(Bc[2], Bc[3], bw1);                                              \
        if (PRE) LOADSC((sc) + 3, Bc);                                         \
        __builtin_amdgcn_sched_barrier(0);                                     \
        const int nt_ = (sc) >> 1;                                             \
        const int e0_ = ((sc) & 1) * 2;                                        \
        acc[0][nt_] = __builtin_amdgcn_mfma_f32_16x16x32_bf16(                 \
            a[0][e0_].s, bw0.s, acc[0][nt_], 0, 0, 0);                         \
        acc[1][nt_] = __builtin_amdgcn_mfma_f32_16x16x32_bf16(                 \
            a[1][e0_].s, bw0.s, acc[1][nt_], 0, 0, 0);                         \
        acc[0][nt_] = __builtin_amdgcn_mfma_f32_16x16x32_bf16(                 \
            a[0][e0_ + 1].s, bw1.s, acc[0][nt_], 0, 0, 0);                     \
        acc[1][nt_] = __builtin_amdgcn_mfma_f32_16x16x32_bf16(                 \
            a[1][e0_ + 1].s, bw1.s, acc[1][nt_], 0, 0, 0);                     \
    }

    STEP(0, B0, 1)
    STEP(1, B1, 1)
    STEP(2, B2, 1)
    STEP(3, B0, 1)
    STEP(4, B1, 1)
    STEP(5, B2, 0)
    STEP(6, B0, 0)
    STEP(7, B1, 0)
#undef STEP
#undef LOADSC

    // D frag: row=b=(l>>4)*4+r (+16*mt), col=k=lr (+16*nt)  [m89 layout]
#pragma unroll
    for (int mt = 0; mt < 2; ++mt)
#pragma unroll
        for (int nt = 0; nt < 4; ++nt)
#pragma unroll
            for (int r = 0; r < 4; ++r)
                T[wv][mt * 16 + lh * 4 + r][nt * 16 + lr] = f2bf(acc[mt][nt][r]);
    __syncthreads();

    // write u[j, d, b, k]: wave tile = 4KB contiguous (lane = 64B run)
    const int b2 = l >> 1;
    const int kh = (l & 1) * 32;
    ushort* up = u + (((size_t)j * ND + d) * NB + b2) * NK + kh;
    const ushort* tp = &T[wv][b2][kh];
#pragma unroll
    for (int i = 0; i < 4; ++i) {
        short8 v = *reinterpret_cast<const short8*>(tp + i * 8);
        *reinterpret_cast<short8*>(up + i * 8) = v;
    }
}

// ---------------- Routing: s[b,d,k] = sum_j softmax_k(u*Vsum) * u ----------
// (verbatim r7; u is [j][d][b][k])
__global__ __launch_bounds__(512) void k_route(const ushort* __restrict__ u,
                                               const float* __restrict__ Vsum,
                                               float* __restrict__ s,
                                               int first) {
    __shared__ float P[8][8][65];
    const int b  = blockIdx.x >> 4;
    const int dg = blockIdx.x & 15;
    const int t  = threadIdx.x;
    const int wv = t >> 6;  // j-group
    const int l  = t & 63;  // k

    float sacc[8];
#pragma unroll
    for (int dd = 0; dd < 8; ++dd) sacc[dd] = 0.0f;

    const size_t JS = (size_t)ND * NB * NK;
    const ushort* ub = u + ((size_t)(wv * 8) * ND + dg * 8) * (NB * NK) +
                       (size_t)b * NK + l;

    if (first) {
        for (int jj = 0; jj < 8; ++jj) {
            const ushort* up = ub + jj * JS;
#pragma unroll
            for (int dd = 0; dd < 8; ++dd) sacc[dd] += bf2f(up[dd * (NB * NK)]);
        }
#pragma unroll
        for (int dd = 0; dd < 8; ++dd) sacc[dd] *= (1.0f / 64.0f);
    } else {
        float vs[8];
#pragma unroll
        for (int dd = 0; dd < 8; ++dd)
            vs[dd] = Vsum[((size_t)b * ND + dg * 8 + dd) * NK + l];

        for (int jj = 0; jj < 8; ++jj) {
            const ushort* up = ub + jj * JS;
            float uv[8];
#pragma unroll
            for (int dd = 0; dd < 8; ++dd) uv[dd] = bf2f(up[dd * (NB * NK)]);
#pragma unroll
            for (int dd = 0; dd < 8; ++dd) {
                // softmax is shift-invariant; constant shift avoids overflow
                float p = __expf(uv[dd] * vs[dd] - 32.0f);
                float q = wave_sum(p);
                sacc[dd] = fmaf(p * __builtin_amdgcn_rcpf(q), uv[dd], sacc[dd]);
            }
        }
    }

#pragma unroll
    for (int dd = 0; dd < 8; ++dd) P[wv][dd][l] = sacc[dd];
    __syncthreads();

    const int dd = t >> 6;
    const int k  = t & 63;
    float r = P[0][dd][k];
#pragma unroll
    for (int w2 = 1; w2 < 8; ++w2) r += P[w2][dd][k];
    s[((size_t)b * ND + dg * 8 + dd) * NK + k] = r;
}

// ---------------- Squash (verbatim r7) -------------------------------------
__global__ __launch_bounds__(256) void k_squash(const float* __restrict__ s,
                                                float* __restrict__ Vsum,
                                                float* __restrict__ out,
                                                int mode) {
    const int t  = threadIdx.x;
    const int gw = blockIdx.x * 4 + (t >> 6);
    const int b  = gw >> 6;
    const int k  = gw & 63;
    const int l  = t & 63;

    const float s0 = s[((size_t)b * ND + l) * NK + k];
    const float s1 = s[((size_t)b * ND + l + 64) * NK + k];
    float sq    = wave_sum(fmaf(s0, s0, s1 * s1));
    float scale = (sq / (1.0f + sq)) * rsqrtf(sq + 1e-9f);
    float v0 = s0 * scale, v1 = s1 * scale;
    if (mode == 2) {
        float* op = out + ((size_t)b * NN + k) * ND;
        op[l]      = v0;
        op[l + 64] = v1;
    } else if (mode == 0) {
        float* vp = Vsum + (size_t)b * ND * NK + k;
        vp[(size_t)l * NK]        = v0;
        vp[(size_t)(l + 64) * NK] = v1;
    } else {
        float* vp = Vsum + (size_t)b * ND * NK + k;
        vp[(size_t)l * NK]        += v0;
        vp[(size_t)(l + 64) * NK] += v1;
    }
}

extern "C" void kernel_launch(void* const* d_in, const int* in_sizes, int n_in,
                              void* d_out, int out_size, void* d_ws, size_t ws_size,
                              hipStream_t stream) {
    (void)in_sizes; (void)n_in; (void)out_size;
    const float* x = (const float*)d_in[0];
    const float* W = (const float*)d_in[1];
    float* out = (float*)d_out;

    if (ws_size < WS_NEED) return;
    char* ws = (char*)d_ws;
    ushort* u   = (ushort*)ws;
    float* Vsum = (float*)(ws + U_BYTES);
    float* s    = (float*)(ws + U_BYTES + V_BYTES);

    k_u<<<dim3(2048), dim3(256), 0, stream>>>(W, x, u);
    for (int it = 0; it < 3; ++it) {
        k_route<<<dim3(512), dim3(512), 0, stream>>>(u, Vsum, s, it == 0 ? 1 : 0);
        k_squash<<<dim3(512), dim3(256), 0, stream>>>(s, Vsum, out, it);
    }
}